// Round 1
// baseline (3567.382 us; speedup 1.0000x reference)
//
#include <hip/hip_runtime.h>

#define D 128
#define TR 64               // GEMM tile rows per block
#define BN_EPS 1e-5f

// ---------------------------------------------------------------------------
// z = h (vector copy); block 0 also zeroes the 256-float stats buffer
// ---------------------------------------------------------------------------
__global__ void copy_zero_stats(const float* __restrict__ h, float* __restrict__ z,
                                float* __restrict__ stats, int n4) {
  int i = blockIdx.x * blockDim.x + threadIdx.x;
  if (i < n4) {
    ((float4*)z)[i] = ((const float4*)h)[i];
  }
  if (blockIdx.x == 0 && threadIdx.x < 256) stats[threadIdx.x] = 0.f;
}

// ---------------------------------------------------------------------------
// z[dst[e]] += h[src[e]]  (COO scatter-add; 32 threads/edge, float4/thread)
// ---------------------------------------------------------------------------
__global__ void scatter_add(const float* __restrict__ h, float* __restrict__ z,
                            const int* __restrict__ src, const int* __restrict__ dst,
                            int E) {
  int tid = blockIdx.x * blockDim.x + threadIdx.x;
  int e = tid >> 5;
  if (e >= E) return;
  int c = (tid & 31) << 2;
  int s = src[e];
  int d = dst[e];
  float4 v = *(const float4*)(h + (size_t)s * D + c);
  float* zp = z + (size_t)d * D + c;
  atomicAdd(zp + 0, v.x);
  atomicAdd(zp + 1, v.y);
  atomicAdd(zp + 2, v.z);
  atomicAdd(zp + 3, v.w);
}

// ---------------------------------------------------------------------------
// Y = Z @ W + bias, and accumulate per-column sum / sumsq into stats[0..255]
// Block: 256 threads, 64 rows x 128 cols tile; thread = 8 rows x 4 cols
// ---------------------------------------------------------------------------
__global__ __launch_bounds__(256) void gemm_bn_stats(
    const float* __restrict__ Z, const float* __restrict__ W,
    const float* __restrict__ bias, float* __restrict__ Y,
    float* __restrict__ stats, int N) {
  __shared__ float Zs[TR][D];
  const int t = threadIdx.x;
  const int block_row = blockIdx.x * TR;

  for (int i = t; i < TR * (D / 4); i += 256) {
    int r = i >> 5;
    int c = (i & 31) << 2;
    int gr = block_row + r;
    float4 v = make_float4(0.f, 0.f, 0.f, 0.f);
    if (gr < N) v = *(const float4*)(Z + (size_t)gr * D + c);
    *(float4*)(&Zs[r][c]) = v;
  }
  __syncthreads();

  const int cg = t & 31;
  const int rg = t >> 5;
  const int c0 = cg << 2;

  float4 bv = *(const float4*)(bias + c0);
  float4 acc[8];
#pragma unroll
  for (int r = 0; r < 8; ++r) acc[r] = bv;

#pragma unroll 4
  for (int k = 0; k < D; ++k) {
    float4 w = *(const float4*)(W + (size_t)k * D + c0);
#pragma unroll
    for (int r = 0; r < 8; ++r) {
      float zv = Zs[rg * 8 + r][k];
      acc[r].x = fmaf(zv, w.x, acc[r].x);
      acc[r].y = fmaf(zv, w.y, acc[r].y);
      acc[r].z = fmaf(zv, w.z, acc[r].z);
      acc[r].w = fmaf(zv, w.w, acc[r].w);
    }
  }

  float s0 = 0.f, s1 = 0.f, s2 = 0.f, s3 = 0.f;
  float q0 = 0.f, q1 = 0.f, q2 = 0.f, q3 = 0.f;
#pragma unroll
  for (int r = 0; r < 8; ++r) {
    int row = block_row + rg * 8 + r;
    if (row < N) {
      *(float4*)(Y + (size_t)row * D + c0) = acc[r];
      s0 += acc[r].x; q0 += acc[r].x * acc[r].x;
      s1 += acc[r].y; q1 += acc[r].y * acc[r].y;
      s2 += acc[r].z; q2 += acc[r].z * acc[r].z;
      s3 += acc[r].w; q3 += acc[r].w * acc[r].w;
    }
  }

  __syncthreads();            // k-loop reads of Zs are done; safe to reuse as scratch
  float* red = &Zs[0][0];     // [0..1023] = sum partials, [1024..2047] = sumsq
  red[rg * D + c0 + 0] = s0;  red[1024 + rg * D + c0 + 0] = q0;
  red[rg * D + c0 + 1] = s1;  red[1024 + rg * D + c0 + 1] = q1;
  red[rg * D + c0 + 2] = s2;  red[1024 + rg * D + c0 + 2] = q2;
  red[rg * D + c0 + 3] = s3;  red[1024 + rg * D + c0 + 3] = q3;
  __syncthreads();
  if (t < D) {
    float ts = 0.f, tq = 0.f;
#pragma unroll
    for (int g = 0; g < 8; ++g) {
      ts += red[g * D + t];
      tq += red[1024 + g * D + t];
    }
    atomicAdd(&stats[t], ts);
    atomicAdd(&stats[D + t], tq);
  }
}

// ---------------------------------------------------------------------------
// From stats -> per-column scale a and shift b:  bn(x) = a*x + b
// ---------------------------------------------------------------------------
__global__ void bn_finalize(const float* __restrict__ stats,
                            const float* __restrict__ gamma,
                            const float* __restrict__ beta,
                            float* __restrict__ ab, float invN) {
  int c = threadIdx.x;
  float mu = stats[c] * invN;
  float var = stats[D + c] * invN - mu * mu;
  var = fmaxf(var, 0.f);
  float inv = rsqrtf(var + BN_EPS);
  float a = gamma[c] * inv;
  ab[c] = a;
  ab[D + c] = beta[c] - mu * a;
}

// ---------------------------------------------------------------------------
// out = maybe_relu( relu(Y*a + b) @ W + bias )
// ---------------------------------------------------------------------------
__global__ __launch_bounds__(256) void gemm_affine_relu(
    const float* __restrict__ Y, const float* __restrict__ ab,
    const float* __restrict__ W, const float* __restrict__ bias,
    float* __restrict__ out, int N, int relu_out) {
  __shared__ float Zs[TR][D];
  const int t = threadIdx.x;
  const int block_row = blockIdx.x * TR;

  for (int i = t; i < TR * (D / 4); i += 256) {
    int r = i >> 5;
    int c = (i & 31) << 2;
    int gr = block_row + r;
    float4 v = make_float4(0.f, 0.f, 0.f, 0.f);
    if (gr < N) v = *(const float4*)(Y + (size_t)gr * D + c);
    float4 av = *(const float4*)(ab + c);
    float4 bv = *(const float4*)(ab + D + c);
    v.x = fmaxf(fmaf(v.x, av.x, bv.x), 0.f);
    v.y = fmaxf(fmaf(v.y, av.y, bv.y), 0.f);
    v.z = fmaxf(fmaf(v.z, av.z, bv.z), 0.f);
    v.w = fmaxf(fmaf(v.w, av.w, bv.w), 0.f);
    *(float4*)(&Zs[r][c]) = v;
  }
  __syncthreads();

  const int cg = t & 31;
  const int rg = t >> 5;
  const int c0 = cg << 2;

  float4 bv = *(const float4*)(bias + c0);
  float4 acc[8];
#pragma unroll
  for (int r = 0; r < 8; ++r) acc[r] = bv;

#pragma unroll 4
  for (int k = 0; k < D; ++k) {
    float4 w = *(const float4*)(W + (size_t)k * D + c0);
#pragma unroll
    for (int r = 0; r < 8; ++r) {
      float zv = Zs[rg * 8 + r][k];
      acc[r].x = fmaf(zv, w.x, acc[r].x);
      acc[r].y = fmaf(zv, w.y, acc[r].y);
      acc[r].z = fmaf(zv, w.z, acc[r].z);
      acc[r].w = fmaf(zv, w.w, acc[r].w);
    }
  }

#pragma unroll
  for (int r = 0; r < 8; ++r) {
    int row = block_row + rg * 8 + r;
    if (row < N) {
      float4 o = acc[r];
      if (relu_out) {
        o.x = fmaxf(o.x, 0.f);
        o.y = fmaxf(o.y, 0.f);
        o.z = fmaxf(o.z, 0.f);
        o.w = fmaxf(o.w, 0.f);
      }
      *(float4*)(out + (size_t)row * D + c0) = o;
    }
  }
}

// ---------------------------------------------------------------------------
extern "C" void kernel_launch(void* const* d_in, const int* in_sizes, int n_in,
                              void* d_out, int out_size, void* d_ws, size_t ws_size,
                              hipStream_t stream) {
  const float* x     = (const float*)d_in[0];
  const float* W1    = (const float*)d_in[1];
  const float* b1    = (const float*)d_in[2];
  const float* gamma = (const float*)d_in[3];
  const float* beta  = (const float*)d_in[4];
  const float* W2    = (const float*)d_in[5];
  const float* b2    = (const float*)d_in[6];
  const int*   ei    = (const int*)d_in[7];

  const int N = in_sizes[0] / D;
  const int E = in_sizes[7] / 2;
  const int* src = ei;        // edge_index[0]
  const int* dst = ei + E;    // edge_index[1]
  float* out = (float*)d_out;

  char* ws = (char*)d_ws;
  size_t bufBytes = (size_t)N * D * sizeof(float);
  float* B0    = (float*)ws;
  float* B1    = (float*)(ws + bufBytes);
  float* stats = (float*)(ws + 2 * bufBytes);   // 256 floats: sum[128], sumsq[128]
  float* ab    = stats + 256;                   // 256 floats: a[128], b[128]

  const int n4 = N * D / 4;
  const int copyBlocks = (n4 + 255) / 256;
  const int scatBlocks = (int)(((long long)E * 32 + 255) / 256);
  const int gemmBlocks = (N + TR - 1) / TR;
  const float invN = 1.f / (float)N;

  const float* h_in = x;
  for (int i = 0; i < 3; ++i) {
    float* Zb = (i == 1) ? B1 : B0;
    float* Yb = (i == 1) ? B0 : B1;
    float* Ob = (i == 0) ? B0 : (i == 1) ? B1 : out;

    copy_zero_stats<<<copyBlocks, 256, 0, stream>>>(h_in, Zb, stats, n4);
    scatter_add<<<scatBlocks, 256, 0, stream>>>(h_in, Zb, src, dst, E);
    gemm_bn_stats<<<gemmBlocks, 256, 0, stream>>>(
        Zb, W1 + (size_t)i * D * D, b1 + (size_t)i * D, Yb, stats, N);
    bn_finalize<<<1, D, 0, stream>>>(stats, gamma + (size_t)i * D,
                                     beta + (size_t)i * D, ab, invN);
    gemm_affine_relu<<<gemmBlocks, 256, 0, stream>>>(
        Yb, ab, W2 + (size_t)i * D * D, b2 + (size_t)i * D, Ob, N, (i < 2) ? 1 : 0);
    h_in = Ob;
  }
}

// Round 2
// 532.917 us; speedup vs baseline: 6.6941x; 6.6941x over previous
//
#include <hip/hip_runtime.h>

#define D 128
#define TR 64               // GEMM tile rows per block
#define BN_EPS 1e-5f
#define SCAN_B 256          // scan block size (elements per block)

// ===========================================================================
// CSR build phase (runs once per launch; scratch aliases into B0)
// ===========================================================================

// zero counts[N] and stats[256]
__global__ void zero_counts(int* __restrict__ counts, float* __restrict__ stats, int n) {
  int i = blockIdx.x * blockDim.x + threadIdx.x;
  if (i < n) counts[i] = 0;
  if (blockIdx.x == 0 && threadIdx.x < 256) stats[threadIdx.x] = 0.f;
}

__global__ void count_edges(const int* __restrict__ dst, int* __restrict__ counts, int E) {
  int e = blockIdx.x * blockDim.x + threadIdx.x;
  if (e < E) atomicAdd(&counts[dst[e]], 1);
}

// per-block exclusive scan of counts -> excl, block totals -> blockSums
__global__ __launch_bounds__(SCAN_B) void scan_blocks(const int* __restrict__ counts,
                                                      int* __restrict__ excl,
                                                      int* __restrict__ blockSums, int n) {
  __shared__ int tmp[SCAN_B];
  int gid = blockIdx.x * SCAN_B + threadIdx.x;
  int v = (gid < n) ? counts[gid] : 0;
  tmp[threadIdx.x] = v;
  __syncthreads();
  for (int off = 1; off < SCAN_B; off <<= 1) {
    int y = (threadIdx.x >= off) ? tmp[threadIdx.x - off] : 0;
    __syncthreads();
    tmp[threadIdx.x] += y;
    __syncthreads();
  }
  if (gid < n) excl[gid] = tmp[threadIdx.x] - v;
  if (threadIdx.x == SCAN_B - 1) blockSums[blockIdx.x] = tmp[SCAN_B - 1];
}

// exclusive scan of blockSums in-place (nb <= SCAN_B)
__global__ __launch_bounds__(SCAN_B) void scan_tops(int* __restrict__ blockSums, int nb) {
  __shared__ int tmp[SCAN_B];
  int v = (threadIdx.x < nb) ? blockSums[threadIdx.x] : 0;
  tmp[threadIdx.x] = v;
  __syncthreads();
  for (int off = 1; off < SCAN_B; off <<= 1) {
    int y = (threadIdx.x >= off) ? tmp[threadIdx.x - off] : 0;
    __syncthreads();
    tmp[threadIdx.x] += y;
    __syncthreads();
  }
  if (threadIdx.x < nb) blockSums[threadIdx.x] = tmp[threadIdx.x] - v;
}

__global__ void add_offsets(const int* __restrict__ excl, const int* __restrict__ blockSums,
                            int* __restrict__ row_ptr, int* __restrict__ cursor,
                            int n, int E) {
  int gid = blockIdx.x * blockDim.x + threadIdx.x;
  if (gid < n) {
    int v = excl[gid] + blockSums[gid >> 8];
    row_ptr[gid] = v;
    cursor[gid] = v;
  }
  if (gid == 0) row_ptr[n] = E;
}

__global__ void fill_edges(const int* __restrict__ src, const int* __restrict__ dst,
                           int* __restrict__ cursor, int* __restrict__ col, int E) {
  int e = blockIdx.x * blockDim.x + threadIdx.x;
  if (e < E) {
    int slot = atomicAdd(&cursor[dst[e]], 1);
    col[slot] = src[e];
  }
}

// ===========================================================================
// z[v] = h[v] + sum_{u in N(v)} h[u]   — one wave per node, float2 per lane
// ===========================================================================
__global__ __launch_bounds__(256) void aggregate(const float* __restrict__ h,
                                                 float* __restrict__ z,
                                                 const int* __restrict__ row_ptr,
                                                 const int* __restrict__ col, int Nn) {
  int node = blockIdx.x * 4 + (threadIdx.x >> 6);
  if (node >= Nn) return;
  int lane = threadIdx.x & 63;
  int off = lane << 1;
  int beg = row_ptr[node];
  int end = row_ptr[node + 1];

  float2 a0 = *(const float2*)(h + (size_t)node * D + off);   // self (eps=0)
  float2 a1 = make_float2(0.f, 0.f);
  int e = beg;
  for (; e + 2 <= end; e += 2) {
    int s0 = col[e];
    int s1 = col[e + 1];
    float2 v0 = *(const float2*)(h + (size_t)s0 * D + off);
    float2 v1 = *(const float2*)(h + (size_t)s1 * D + off);
    a0.x += v0.x; a0.y += v0.y;
    a1.x += v1.x; a1.y += v1.y;
  }
  if (e < end) {
    int s = col[e];
    float2 v = *(const float2*)(h + (size_t)s * D + off);
    a0.x += v.x; a0.y += v.y;
  }
  a0.x += a1.x; a0.y += a1.y;
  *(float2*)(z + (size_t)node * D + off) = a0;
}

// ===========================================================================
// Y = Z @ W + bias, accumulate per-column sum / sumsq into stats[0..255]
// ===========================================================================
__global__ __launch_bounds__(256) void gemm_bn_stats(
    const float* __restrict__ Z, const float* __restrict__ W,
    const float* __restrict__ bias, float* __restrict__ Y,
    float* __restrict__ stats, int N) {
  __shared__ float Zs[TR][D];
  const int t = threadIdx.x;
  const int block_row = blockIdx.x * TR;

  for (int i = t; i < TR * (D / 4); i += 256) {
    int r = i >> 5;
    int c = (i & 31) << 2;
    int gr = block_row + r;
    float4 v = make_float4(0.f, 0.f, 0.f, 0.f);
    if (gr < N) v = *(const float4*)(Z + (size_t)gr * D + c);
    *(float4*)(&Zs[r][c]) = v;
  }
  __syncthreads();

  const int cg = t & 31;
  const int rg = t >> 5;
  const int c0 = cg << 2;

  float4 bv = *(const float4*)(bias + c0);
  float4 acc[8];
#pragma unroll
  for (int r = 0; r < 8; ++r) acc[r] = bv;

#pragma unroll 4
  for (int k = 0; k < D; ++k) {
    float4 w = *(const float4*)(W + (size_t)k * D + c0);
#pragma unroll
    for (int r = 0; r < 8; ++r) {
      float zv = Zs[rg * 8 + r][k];
      acc[r].x = fmaf(zv, w.x, acc[r].x);
      acc[r].y = fmaf(zv, w.y, acc[r].y);
      acc[r].z = fmaf(zv, w.z, acc[r].z);
      acc[r].w = fmaf(zv, w.w, acc[r].w);
    }
  }

  float s0 = 0.f, s1 = 0.f, s2 = 0.f, s3 = 0.f;
  float q0 = 0.f, q1 = 0.f, q2 = 0.f, q3 = 0.f;
#pragma unroll
  for (int r = 0; r < 8; ++r) {
    int row = block_row + rg * 8 + r;
    if (row < N) {
      *(float4*)(Y + (size_t)row * D + c0) = acc[r];
      s0 += acc[r].x; q0 += acc[r].x * acc[r].x;
      s1 += acc[r].y; q1 += acc[r].y * acc[r].y;
      s2 += acc[r].z; q2 += acc[r].z * acc[r].z;
      s3 += acc[r].w; q3 += acc[r].w * acc[r].w;
    }
  }

  __syncthreads();
  float* red = &Zs[0][0];
  red[rg * D + c0 + 0] = s0;  red[1024 + rg * D + c0 + 0] = q0;
  red[rg * D + c0 + 1] = s1;  red[1024 + rg * D + c0 + 1] = q1;
  red[rg * D + c0 + 2] = s2;  red[1024 + rg * D + c0 + 2] = q2;
  red[rg * D + c0 + 3] = s3;  red[1024 + rg * D + c0 + 3] = q3;
  __syncthreads();
  if (t < D) {
    float ts = 0.f, tq = 0.f;
#pragma unroll
    for (int g = 0; g < 8; ++g) {
      ts += red[g * D + t];
      tq += red[1024 + g * D + t];
    }
    atomicAdd(&stats[t], ts);
    atomicAdd(&stats[D + t], tq);
  }
}

// ---------------------------------------------------------------------------
// stats -> bn(x) = a*x + b; then zero stats for the next layer
// ---------------------------------------------------------------------------
__global__ void bn_finalize(float* __restrict__ stats,
                            const float* __restrict__ gamma,
                            const float* __restrict__ beta,
                            float* __restrict__ ab, float invN) {
  int c = threadIdx.x;
  float mu = stats[c] * invN;
  float var = stats[D + c] * invN - mu * mu;
  var = fmaxf(var, 0.f);
  float inv = rsqrtf(var + BN_EPS);
  float a = gamma[c] * inv;
  ab[c] = a;
  ab[D + c] = beta[c] - mu * a;
  stats[c] = 0.f;
  stats[D + c] = 0.f;
}

// ---------------------------------------------------------------------------
// out = maybe_relu( relu(Y*a + b) @ W + bias )
// ---------------------------------------------------------------------------
__global__ __launch_bounds__(256) void gemm_affine_relu(
    const float* __restrict__ Y, const float* __restrict__ ab,
    const float* __restrict__ W, const float* __restrict__ bias,
    float* __restrict__ out, int N, int relu_out) {
  __shared__ float Zs[TR][D];
  const int t = threadIdx.x;
  const int block_row = blockIdx.x * TR;

  for (int i = t; i < TR * (D / 4); i += 256) {
    int r = i >> 5;
    int c = (i & 31) << 2;
    int gr = block_row + r;
    float4 v = make_float4(0.f, 0.f, 0.f, 0.f);
    if (gr < N) v = *(const float4*)(Y + (size_t)gr * D + c);
    float4 av = *(const float4*)(ab + c);
    float4 bv = *(const float4*)(ab + D + c);
    v.x = fmaxf(fmaf(v.x, av.x, bv.x), 0.f);
    v.y = fmaxf(fmaf(v.y, av.y, bv.y), 0.f);
    v.z = fmaxf(fmaf(v.z, av.z, bv.z), 0.f);
    v.w = fmaxf(fmaf(v.w, av.w, bv.w), 0.f);
    *(float4*)(&Zs[r][c]) = v;
  }
  __syncthreads();

  const int cg = t & 31;
  const int rg = t >> 5;
  const int c0 = cg << 2;

  float4 bv = *(const float4*)(bias + c0);
  float4 acc[8];
#pragma unroll
  for (int r = 0; r < 8; ++r) acc[r] = bv;

#pragma unroll 4
  for (int k = 0; k < D; ++k) {
    float4 w = *(const float4*)(W + (size_t)k * D + c0);
#pragma unroll
    for (int r = 0; r < 8; ++r) {
      float zv = Zs[rg * 8 + r][k];
      acc[r].x = fmaf(zv, w.x, acc[r].x);
      acc[r].y = fmaf(zv, w.y, acc[r].y);
      acc[r].z = fmaf(zv, w.z, acc[r].z);
      acc[r].w = fmaf(zv, w.w, acc[r].w);
    }
  }

#pragma unroll
  for (int r = 0; r < 8; ++r) {
    int row = block_row + rg * 8 + r;
    if (row < N) {
      float4 o = acc[r];
      if (relu_out) {
        o.x = fmaxf(o.x, 0.f);
        o.y = fmaxf(o.y, 0.f);
        o.z = fmaxf(o.z, 0.f);
        o.w = fmaxf(o.w, 0.f);
      }
      *(float4*)(out + (size_t)row * D + c0) = o;
    }
  }
}

// ===========================================================================
extern "C" void kernel_launch(void* const* d_in, const int* in_sizes, int n_in,
                              void* d_out, int out_size, void* d_ws, size_t ws_size,
                              hipStream_t stream) {
  const float* x     = (const float*)d_in[0];
  const float* W1    = (const float*)d_in[1];
  const float* b1    = (const float*)d_in[2];
  const float* gamma = (const float*)d_in[3];
  const float* beta  = (const float*)d_in[4];
  const float* W2    = (const float*)d_in[5];
  const float* b2    = (const float*)d_in[6];
  const int*   ei    = (const int*)d_in[7];

  const int N = in_sizes[0] / D;
  const int E = in_sizes[7] / 2;
  const int* src = ei;        // edge_index[0]
  const int* dst = ei + E;    // edge_index[1]
  float* out = (float*)d_out;

  char* ws = (char*)d_ws;
  size_t bufBytes = (size_t)N * D * sizeof(float);
  float* B0    = (float*)ws;
  float* B1    = (float*)(ws + bufBytes);
  float* stats = (float*)(ws + 2 * bufBytes);   // 256 floats
  float* ab    = stats + 256;                   // 256 floats
  int* row_ptr = (int*)(ws + 2 * bufBytes + 2048);  // N+1 ints
  int* col     = row_ptr + (N + 1);                 // E ints
  // build-phase scratch aliases B0 (dead until first aggregate writes it)
  int* counts    = (int*)B0;
  int* excl      = counts + N;
  int* cursor    = excl + N;
  int* blockSums = cursor + N;                  // SCAN_B ints

  const int nb = (N + SCAN_B - 1) / SCAN_B;     // 196 <= SCAN_B
  const int eb = (E + 255) / 256;
  const int aggBlocks = (N + 3) / 4;
  const int gemmBlocks = (N + TR - 1) / TR;
  const float invN = 1.f / (float)N;

  // ---- CSR build ----
  zero_counts<<<(N + 255) / 256, 256, 0, stream>>>(counts, stats, N);
  count_edges<<<eb, 256, 0, stream>>>(dst, counts, E);
  scan_blocks<<<nb, SCAN_B, 0, stream>>>(counts, excl, blockSums, N);
  scan_tops<<<1, SCAN_B, 0, stream>>>(blockSums, nb);
  add_offsets<<<(N + 255) / 256, 256, 0, stream>>>(excl, blockSums, row_ptr, cursor, N, E);
  fill_edges<<<eb, 256, 0, stream>>>(src, dst, cursor, col, E);

  // ---- layers ----
  const float* h_in = x;
  for (int i = 0; i < 3; ++i) {
    // ping-pong: layer0: x->B0->B1->B0 ; layer1: B0->B1->B0->B1 ; layer2: B1->B0->B1->out
    float* Zb = (i == 1) ? B1 : B0;   // agg output
    float* Yb = (i == 1) ? B0 : B1;   // gemm1 output
    float* Ob = (i == 0) ? B0 : (i == 1) ? B1 : out;

    aggregate<<<aggBlocks, 256, 0, stream>>>(h_in, Zb, row_ptr, col, N);
    gemm_bn_stats<<<gemmBlocks, 256, 0, stream>>>(
        Zb, W1 + (size_t)i * D * D, b1 + (size_t)i * D, Yb, stats, N);
    bn_finalize<<<1, D, 0, stream>>>(stats, gamma + (size_t)i * D,
                                     beta + (size_t)i * D, ab, invN);
    gemm_affine_relu<<<gemmBlocks, 256, 0, stream>>>(
        Yb, ab, W2 + (size_t)i * D * D, b2 + (size_t)i * D, Ob, N, (i < 2) ? 1 : 0);
    h_in = Ob;
  }
}

// Round 3
// 459.204 us; speedup vs baseline: 7.7686x; 1.1605x over previous
//
#include <hip/hip_runtime.h>

#define D 128
#define TR 64               // GEMM tile rows per block
#define BN_EPS 1e-5f
#define SCAN_B 256

typedef __bf16 bf16_t;
typedef __bf16 bf16x8 __attribute__((ext_vector_type(8)));
typedef __bf16 bf16x4 __attribute__((ext_vector_type(4)));
typedef float floatx4 __attribute__((ext_vector_type(4)));

// ===========================================================================
// CSR build phase (scratch aliases into B0)
// ===========================================================================
__global__ void zero_counts(int* __restrict__ counts, float* __restrict__ stats, int n) {
  int i = blockIdx.x * blockDim.x + threadIdx.x;
  if (i < n) counts[i] = 0;
  if (blockIdx.x == 0 && threadIdx.x < 256) stats[threadIdx.x] = 0.f;
}

__global__ void count_edges(const int* __restrict__ dst, int* __restrict__ counts, int E) {
  int e = blockIdx.x * blockDim.x + threadIdx.x;
  if (e < E) atomicAdd(&counts[dst[e]], 1);
}

__global__ __launch_bounds__(SCAN_B) void scan_blocks(const int* __restrict__ counts,
                                                      int* __restrict__ excl,
                                                      int* __restrict__ blockSums, int n) {
  __shared__ int tmp[SCAN_B];
  int gid = blockIdx.x * SCAN_B + threadIdx.x;
  int v = (gid < n) ? counts[gid] : 0;
  tmp[threadIdx.x] = v;
  __syncthreads();
  for (int off = 1; off < SCAN_B; off <<= 1) {
    int y = (threadIdx.x >= off) ? tmp[threadIdx.x - off] : 0;
    __syncthreads();
    tmp[threadIdx.x] += y;
    __syncthreads();
  }
  if (gid < n) excl[gid] = tmp[threadIdx.x] - v;
  if (threadIdx.x == SCAN_B - 1) blockSums[blockIdx.x] = tmp[SCAN_B - 1];
}

__global__ __launch_bounds__(SCAN_B) void scan_tops(int* __restrict__ blockSums, int nb) {
  __shared__ int tmp[SCAN_B];
  int v = (threadIdx.x < nb) ? blockSums[threadIdx.x] : 0;
  tmp[threadIdx.x] = v;
  __syncthreads();
  for (int off = 1; off < SCAN_B; off <<= 1) {
    int y = (threadIdx.x >= off) ? tmp[threadIdx.x - off] : 0;
    __syncthreads();
    tmp[threadIdx.x] += y;
    __syncthreads();
  }
  if (threadIdx.x < nb) blockSums[threadIdx.x] = tmp[threadIdx.x] - v;
}

__global__ void add_offsets(const int* __restrict__ excl, const int* __restrict__ blockSums,
                            int* __restrict__ row_ptr, int* __restrict__ cursor,
                            int n, int E) {
  int gid = blockIdx.x * blockDim.x + threadIdx.x;
  if (gid < n) {
    int v = excl[gid] + blockSums[gid >> 8];
    row_ptr[gid] = v;
    cursor[gid] = v;
  }
  if (gid == 0) row_ptr[n] = E;
}

__global__ void fill_edges(const int* __restrict__ src, const int* __restrict__ dst,
                           int* __restrict__ cursor, int* __restrict__ col, int E) {
  int e = blockIdx.x * blockDim.x + threadIdx.x;
  if (e < E) {
    int slot = atomicAdd(&cursor[dst[e]], 1);
    col[slot] = src[e];
  }
}

// ===========================================================================
// Pre-swizzle weights into B-fragment order, bf16.
// Frag layout for mfma_f32_16x16x32_bf16 B-operand: lane = quad*16 + (n&15)
// holds B[k = kc*32 + quad*8 + j][n], j=0..7. Storage:
// Wsw[mat][ ((ntile*4+kc)*64 + lane)*8 + j ]
// ===========================================================================
__global__ void swizzle_weights(const float* __restrict__ W1, const float* __restrict__ W2,
                                bf16_t* __restrict__ Wsw) {
  int i = blockIdx.x * blockDim.x + threadIdx.x;
  if (i >= 6 * 16384) return;
  int mat = i >> 14;
  int kn = i & 16383;
  int k = kn >> 7;
  int n = kn & 127;
  const float* Wm = (mat < 3) ? (W1 + (size_t)mat * 16384) : (W2 + (size_t)(mat - 3) * 16384);
  float v = Wm[kn];
  int f = ((n >> 4) << 2) | (k >> 5);
  int lane = (((k >> 3) & 3) << 4) | (n & 15);
  int j = k & 7;
  Wsw[(size_t)mat * 16384 + ((f << 6) + lane) * 8 + j] = (bf16_t)v;
}

// ===========================================================================
// z[v] = h[v] + sum_{u in N(v)} h[u]   — one wave per node, float2 per lane
// ===========================================================================
__global__ __launch_bounds__(256) void aggregate(const float* __restrict__ h,
                                                 float* __restrict__ z,
                                                 const int* __restrict__ row_ptr,
                                                 const int* __restrict__ col, int Nn) {
  int node = blockIdx.x * 4 + (threadIdx.x >> 6);
  if (node >= Nn) return;
  int lane = threadIdx.x & 63;
  int off = lane << 1;
  int beg = row_ptr[node];
  int end = row_ptr[node + 1];

  float2 a0 = *(const float2*)(h + (size_t)node * D + off);
  float2 a1 = make_float2(0.f, 0.f);
  int e = beg;
  for (; e + 2 <= end; e += 2) {
    int s0 = col[e];
    int s1 = col[e + 1];
    float2 v0 = *(const float2*)(h + (size_t)s0 * D + off);
    float2 v1 = *(const float2*)(h + (size_t)s1 * D + off);
    a0.x += v0.x; a0.y += v0.y;
    a1.x += v1.x; a1.y += v1.y;
  }
  if (e < end) {
    int s = col[e];
    float2 v = *(const float2*)(h + (size_t)s * D + off);
    a0.x += v.x; a0.y += v.y;
  }
  a0.x += a1.x; a0.y += a1.y;
  *(float2*)(z + (size_t)node * D + off) = a0;
}

// ===========================================================================
// MFMA GEMM 1: Y = Z @ W + bias  (fp32 in/out, bf16 MFMA), + BN column stats
// Block 256 = 4 waves; tile 64 rows x 128 cols; wave = 16 rows.
// ===========================================================================
__device__ __forceinline__ bf16_t f2bf(float f) { return (bf16_t)f; }

__global__ __launch_bounds__(256) void gemm1_mfma(
    const float* __restrict__ Z, const bf16_t* __restrict__ Wsw,
    const float* __restrict__ bias, float* __restrict__ Y,
    float* __restrict__ stats, int N) {
  __shared__ bf16_t As[TR][136];     // +8 pad: 2-way-conflict-free ds_read_b128
  __shared__ float sred[256];
  const int t = threadIdx.x;
  const int block_row = blockIdx.x * TR;

  if (t < 256) sred[t] = 0.f;

  // stage Z tile -> bf16 LDS
  for (int i = t; i < TR * 32; i += 256) {
    int r = i >> 5;
    int c = (i & 31) << 2;
    int gr = block_row + r;
    float4 v = make_float4(0.f, 0.f, 0.f, 0.f);
    if (gr < N) v = *(const float4*)(Z + (size_t)gr * D + c);
    bf16x4 p;
    p[0] = f2bf(v.x); p[1] = f2bf(v.y); p[2] = f2bf(v.z); p[3] = f2bf(v.w);
    *(bf16x4*)&As[r][c] = p;
  }
  __syncthreads();

  const int wv = t >> 6;
  const int lane = t & 63;
  const int l15 = lane & 15;
  const int quad = lane >> 4;

  bf16x8 a[4];
#pragma unroll
  for (int kc = 0; kc < 4; ++kc)
    a[kc] = *(const bf16x8*)&As[wv * 16 + l15][kc * 32 + quad * 8];

  floatx4 acc[8];
#pragma unroll
  for (int nt = 0; nt < 8; ++nt) {
    float bv = bias[nt * 16 + l15];
    acc[nt] = (floatx4){bv, bv, bv, bv};
  }

#pragma unroll
  for (int nt = 0; nt < 8; ++nt) {
#pragma unroll
    for (int kc = 0; kc < 4; ++kc) {
      bf16x8 b = *(const bf16x8*)(Wsw + (size_t)((nt * 4 + kc) * 64 + lane) * 8);
      acc[nt] = __builtin_amdgcn_mfma_f32_16x16x32_bf16(a[kc], b, acc[nt], 0, 0, 0);
    }
  }

  // epilogue: C/D layout col = lane&15 (+nt*16), row = quad*4 + reg
  const int rowBase = block_row + wv * 16 + quad * 4;
#pragma unroll
  for (int nt = 0; nt < 8; ++nt) {
    int c = nt * 16 + l15;
    float s = 0.f, q = 0.f;
#pragma unroll
    for (int r = 0; r < 4; ++r) {
      int row = rowBase + r;
      if (row < N) {
        float v = acc[nt][r];
        Y[(size_t)row * D + c] = v;
        s += v; q += v * v;
      }
    }
    s += __shfl_xor(s, 16); s += __shfl_xor(s, 32);
    q += __shfl_xor(q, 16); q += __shfl_xor(q, 32);
    if (quad == 0) {
      atomicAdd(&sred[c], s);
      atomicAdd(&sred[128 + c], q);
    }
  }
  __syncthreads();
  if (t < 256) atomicAdd(&stats[t], sred[t]);
}

// ---------------------------------------------------------------------------
// stats -> bn(x) = a*x + b; zero stats for next layer
// ---------------------------------------------------------------------------
__global__ void bn_finalize(float* __restrict__ stats,
                            const float* __restrict__ gamma,
                            const float* __restrict__ beta,
                            float* __restrict__ ab, float invN) {
  int c = threadIdx.x;
  float mu = stats[c] * invN;
  float var = stats[D + c] * invN - mu * mu;
  var = fmaxf(var, 0.f);
  float inv = rsqrtf(var + BN_EPS);
  float a = gamma[c] * inv;
  ab[c] = a;
  ab[D + c] = beta[c] - mu * a;
  stats[c] = 0.f;
  stats[D + c] = 0.f;
}

// ===========================================================================
// MFMA GEMM 2: out = maybe_relu( relu(Y*a + b) @ W + bias )
// ===========================================================================
__global__ __launch_bounds__(256) void gemm2_mfma(
    const float* __restrict__ Yin, const float* __restrict__ ab,
    const bf16_t* __restrict__ Wsw, const float* __restrict__ bias,
    float* __restrict__ out, int N, int relu_out) {
  __shared__ bf16_t As[TR][136];
  const int t = threadIdx.x;
  const int block_row = blockIdx.x * TR;

  for (int i = t; i < TR * 32; i += 256) {
    int r = i >> 5;
    int c = (i & 31) << 2;
    int gr = block_row + r;
    float4 v = make_float4(0.f, 0.f, 0.f, 0.f);
    if (gr < N) v = *(const float4*)(Yin + (size_t)gr * D + c);
    float4 av = *(const float4*)(ab + c);
    float4 bv = *(const float4*)(ab + D + c);
    v.x = fmaxf(fmaf(v.x, av.x, bv.x), 0.f);
    v.y = fmaxf(fmaf(v.y, av.y, bv.y), 0.f);
    v.z = fmaxf(fmaf(v.z, av.z, bv.z), 0.f);
    v.w = fmaxf(fmaf(v.w, av.w, bv.w), 0.f);
    bf16x4 p;
    p[0] = f2bf(v.x); p[1] = f2bf(v.y); p[2] = f2bf(v.z); p[3] = f2bf(v.w);
    *(bf16x4*)&As[r][c] = p;
  }
  __syncthreads();

  const int wv = t >> 6;
  const int lane = t & 63;
  const int l15 = lane & 15;
  const int quad = lane >> 4;

  bf16x8 a[4];
#pragma unroll
  for (int kc = 0; kc < 4; ++kc)
    a[kc] = *(const bf16x8*)&As[wv * 16 + l15][kc * 32 + quad * 8];

  floatx4 acc[8];
#pragma unroll
  for (int nt = 0; nt < 8; ++nt) {
    float bv = bias[nt * 16 + l15];
    acc[nt] = (floatx4){bv, bv, bv, bv};
  }

#pragma unroll
  for (int nt = 0; nt < 8; ++nt) {
#pragma unroll
    for (int kc = 0; kc < 4; ++kc) {
      bf16x8 b = *(const bf16x8*)(Wsw + (size_t)((nt * 4 + kc) * 64 + lane) * 8);
      acc[nt] = __builtin_amdgcn_mfma_f32_16x16x32_bf16(a[kc], b, acc[nt], 0, 0, 0);
    }
  }

  const int rowBase = block_row + wv * 16 + quad * 4;
#pragma unroll
  for (int nt = 0; nt < 8; ++nt) {
    int c = nt * 16 + l15;
#pragma unroll
    for (int r = 0; r < 4; ++r) {
      int row = rowBase + r;
      if (row < N) {
        float v = acc[nt][r];
        if (relu_out) v = fmaxf(v, 0.f);
        out[(size_t)row * D + c] = v;
      }
    }
  }
}

// ===========================================================================
extern "C" void kernel_launch(void* const* d_in, const int* in_sizes, int n_in,
                              void* d_out, int out_size, void* d_ws, size_t ws_size,
                              hipStream_t stream) {
  const float* x     = (const float*)d_in[0];
  const float* W1    = (const float*)d_in[1];
  const float* b1    = (const float*)d_in[2];
  const float* gamma = (const float*)d_in[3];
  const float* beta  = (const float*)d_in[4];
  const float* W2    = (const float*)d_in[5];
  const float* b2    = (const float*)d_in[6];
  const int*   ei    = (const int*)d_in[7];

  const int N = in_sizes[0] / D;
  const int E = in_sizes[7] / 2;
  const int* src = ei;
  const int* dst = ei + E;
  float* out = (float*)d_out;

  char* ws = (char*)d_ws;
  size_t bufBytes = (size_t)N * D * sizeof(float);
  float* B0    = (float*)ws;
  float* B1    = (float*)(ws + bufBytes);
  float* stats = (float*)(ws + 2 * bufBytes);       // 256 floats
  float* ab    = stats + 256;                       // 256 floats
  bf16_t* Wsw  = (bf16_t*)(ws + 2 * bufBytes + 2048);  // 6*16384 bf16 = 192 KB (16B-aligned)
  int* row_ptr = (int*)(ws + 2 * bufBytes + 2048 + 6 * 16384 * sizeof(bf16_t)); // N+1
  int* col     = row_ptr + (N + 1);                 // E ints
  // build-phase scratch aliases B0
  int* counts    = (int*)B0;
  int* excl      = counts + N;
  int* cursor    = excl + N;
  int* blockSums = cursor + N;

  const int nb = (N + SCAN_B - 1) / SCAN_B;
  const int eb = (E + 255) / 256;
  const int aggBlocks = (N + 3) / 4;
  const int gemmBlocks = (N + TR - 1) / TR;
  const float invN = 1.f / (float)N;

  // ---- CSR build + weight swizzle ----
  zero_counts<<<(N + 255) / 256, 256, 0, stream>>>(counts, stats, N);
  count_edges<<<eb, 256, 0, stream>>>(dst, counts, E);
  swizzle_weights<<<(6 * 16384 + 255) / 256, 256, 0, stream>>>(W1, W2, Wsw);
  scan_blocks<<<nb, SCAN_B, 0, stream>>>(counts, excl, blockSums, N);
  scan_tops<<<1, SCAN_B, 0, stream>>>(blockSums, nb);
  add_offsets<<<(N + 255) / 256, 256, 0, stream>>>(excl, blockSums, row_ptr, cursor, N, E);
  fill_edges<<<eb, 256, 0, stream>>>(src, dst, cursor, col, E);

  // ---- layers ----
  const float* h_in = x;
  for (int i = 0; i < 3; ++i) {
    float* Zb = (i == 1) ? B1 : B0;
    float* Yb = (i == 1) ? B0 : B1;
    float* Ob = (i == 0) ? B0 : (i == 1) ? B1 : out;

    aggregate<<<aggBlocks, 256, 0, stream>>>(h_in, Zb, row_ptr, col, N);
    gemm1_mfma<<<gemmBlocks, 256, 0, stream>>>(
        Zb, Wsw + (size_t)i * 16384, b1 + (size_t)i * D, Yb, stats, N);
    bn_finalize<<<1, D, 0, stream>>>(stats, gamma + (size_t)i * D,
                                     beta + (size_t)i * D, ab, invN);
    gemm2_mfma<<<gemmBlocks, 256, 0, stream>>>(
        Yb, ab, Wsw + (size_t)(i + 3) * 16384, b2 + (size_t)i * D, Ob, N, (i < 2) ? 1 : 0);
    h_in = Ob;
  }
}

// Round 4
// 420.150 us; speedup vs baseline: 8.4907x; 1.0930x over previous
//
#include <hip/hip_runtime.h>

#define D 128
#define TR 64               // GEMM tile rows per block
#define BN_EPS 1e-5f
#define SCAN_B 256

typedef __bf16 bf16_t;
typedef __bf16 bf16x8 __attribute__((ext_vector_type(8)));
typedef __bf16 bf16x2 __attribute__((ext_vector_type(2)));
typedef float floatx4 __attribute__((ext_vector_type(4)));

// ===========================================================================
// CSR build phase (scratch aliases into the z buffer)
// ===========================================================================
__global__ void zero_counts(int* __restrict__ counts, float* __restrict__ stats, int n) {
  int i = blockIdx.x * blockDim.x + threadIdx.x;
  if (i < n) counts[i] = 0;
  if (blockIdx.x == 0 && threadIdx.x < 256) stats[threadIdx.x] = 0.f;
}

__global__ void count_edges(const int* __restrict__ dst, int* __restrict__ counts, int E) {
  int e = blockIdx.x * blockDim.x + threadIdx.x;
  if (e < E) atomicAdd(&counts[dst[e]], 1);
}

__global__ __launch_bounds__(SCAN_B) void scan_blocks(const int* __restrict__ counts,
                                                      int* __restrict__ excl,
                                                      int* __restrict__ blockSums, int n) {
  __shared__ int tmp[SCAN_B];
  int gid = blockIdx.x * SCAN_B + threadIdx.x;
  int v = (gid < n) ? counts[gid] : 0;
  tmp[threadIdx.x] = v;
  __syncthreads();
  for (int off = 1; off < SCAN_B; off <<= 1) {
    int y = (threadIdx.x >= off) ? tmp[threadIdx.x - off] : 0;
    __syncthreads();
    tmp[threadIdx.x] += y;
    __syncthreads();
  }
  if (gid < n) excl[gid] = tmp[threadIdx.x] - v;
  if (threadIdx.x == SCAN_B - 1) blockSums[blockIdx.x] = tmp[SCAN_B - 1];
}

__global__ __launch_bounds__(SCAN_B) void scan_tops(int* __restrict__ blockSums, int nb) {
  __shared__ int tmp[SCAN_B];
  int v = (threadIdx.x < nb) ? blockSums[threadIdx.x] : 0;
  tmp[threadIdx.x] = v;
  __syncthreads();
  for (int off = 1; off < SCAN_B; off <<= 1) {
    int y = (threadIdx.x >= off) ? tmp[threadIdx.x - off] : 0;
    __syncthreads();
    tmp[threadIdx.x] += y;
    __syncthreads();
  }
  if (threadIdx.x < nb) blockSums[threadIdx.x] = tmp[threadIdx.x] - v;
}

__global__ void add_offsets(const int* __restrict__ excl, const int* __restrict__ blockSums,
                            int* __restrict__ row_ptr, int* __restrict__ cursor,
                            int n, int E) {
  int gid = blockIdx.x * blockDim.x + threadIdx.x;
  if (gid < n) {
    int v = excl[gid] + blockSums[gid >> 8];
    row_ptr[gid] = v;
    cursor[gid] = v;
  }
  if (gid == 0) row_ptr[n] = E;
}

__global__ void fill_edges(const int* __restrict__ src, const int* __restrict__ dst,
                           int* __restrict__ cursor, int* __restrict__ col, int E) {
  int e = blockIdx.x * blockDim.x + threadIdx.x;
  if (e < E) {
    int slot = atomicAdd(&cursor[dst[e]], 1);
    col[slot] = src[e];
  }
}

// x (fp32) -> hb (bf16)
__global__ void x2b(const float* __restrict__ x, bf16_t* __restrict__ hb, int n4) {
  int i = blockIdx.x * blockDim.x + threadIdx.x;
  if (i < n4) {
    float4 v = ((const float4*)x)[i];
    bf16x2 p0, p1;
    p0[0] = (bf16_t)v.x; p0[1] = (bf16_t)v.y;
    p1[0] = (bf16_t)v.z; p1[1] = (bf16_t)v.w;
    ((bf16x2*)hb)[2 * i] = p0;
    ((bf16x2*)hb)[2 * i + 1] = p1;
  }
}

// ===========================================================================
// Pre-swizzle weights into B-fragment order, bf16 (see R3 notes)
// ===========================================================================
__global__ void swizzle_weights(const float* __restrict__ W1, const float* __restrict__ W2,
                                bf16_t* __restrict__ Wsw) {
  int i = blockIdx.x * blockDim.x + threadIdx.x;
  if (i >= 6 * 16384) return;
  int mat = i >> 14;
  int kn = i & 16383;
  int k = kn >> 7;
  int n = kn & 127;
  const float* Wm = (mat < 3) ? (W1 + (size_t)mat * 16384) : (W2 + (size_t)(mat - 3) * 16384);
  float v = Wm[kn];
  int f = ((n >> 4) << 2) | (k >> 5);
  int lane = (((k >> 3) & 3) << 4) | (n & 15);
  int j = k & 7;
  Wsw[(size_t)mat * 16384 + ((f << 6) + lane) * 8 + j] = (bf16_t)v;
}

// ===========================================================================
// z[v] = h[v] + sum_{u in N(v)} h[u]  — one wave/node, bf16x2/lane, fp32 accum
// ===========================================================================
__global__ __launch_bounds__(256) void aggregate(const bf16_t* __restrict__ h,
                                                 bf16_t* __restrict__ z,
                                                 const int* __restrict__ row_ptr,
                                                 const int* __restrict__ col, int Nn) {
  int node = blockIdx.x * 4 + (threadIdx.x >> 6);
  if (node >= Nn) return;
  int lane = threadIdx.x & 63;
  int off = lane << 1;
  int beg = row_ptr[node];
  int end = row_ptr[node + 1];

  bf16x2 sv = *(const bf16x2*)(h + (size_t)node * D + off);
  float ax = (float)sv[0], ay = (float)sv[1];
  float bx = 0.f, by = 0.f;
  int e = beg;
  for (; e + 2 <= end; e += 2) {
    int s0 = col[e];
    int s1 = col[e + 1];
    bf16x2 v0 = *(const bf16x2*)(h + (size_t)s0 * D + off);
    bf16x2 v1 = *(const bf16x2*)(h + (size_t)s1 * D + off);
    ax += (float)v0[0]; ay += (float)v0[1];
    bx += (float)v1[0]; by += (float)v1[1];
  }
  if (e < end) {
    bf16x2 v = *(const bf16x2*)(h + (size_t)col[e] * D + off);
    ax += (float)v[0]; ay += (float)v[1];
  }
  ax += bx; ay += by;
  bf16x2 o;
  o[0] = (bf16_t)ax; o[1] = (bf16_t)ay;
  *(bf16x2*)(z + (size_t)node * D + off) = o;
}

// ===========================================================================
// GEMM 1: Y(bf16) = Z(bf16) @ W + bias, + BN column stats (fp32)
// Block 256 = 4 waves; tile 64 rows x 128 cols; wave = 16 rows.
// ===========================================================================
__global__ __launch_bounds__(256) void gemm1_mfma(
    const bf16_t* __restrict__ Z, const bf16_t* __restrict__ Wsw,
    const float* __restrict__ bias, bf16_t* __restrict__ Y,
    float* __restrict__ stats, int N) {
  __shared__ bf16_t As[TR][136];     // +8 pad for ds_read_b128
  __shared__ float sred[256];
  const int t = threadIdx.x;
  const int block_row = blockIdx.x * TR;

  sred[t] = 0.f;

  // stage Z tile (pure 16B copies)
  for (int i = t; i < TR * 16; i += 256) {
    int r = i >> 4;
    int c = (i & 15) << 3;
    int gr = block_row + r;
    uint4 v = make_uint4(0, 0, 0, 0);
    if (gr < N) v = *(const uint4*)(Z + (size_t)gr * D + c);
    *(uint4*)&As[r][c] = v;
  }
  __syncthreads();

  const int wv = t >> 6;
  const int lane = t & 63;
  const int l15 = lane & 15;
  const int quad = lane >> 4;

  bf16x8 a[4];
#pragma unroll
  for (int kc = 0; kc < 4; ++kc)
    a[kc] = *(const bf16x8*)&As[wv * 16 + l15][kc * 32 + quad * 8];

  floatx4 acc[8];
#pragma unroll
  for (int nt = 0; nt < 8; ++nt) {
    float bv = bias[nt * 16 + l15];
    acc[nt] = (floatx4){bv, bv, bv, bv};
  }

#pragma unroll
  for (int nt = 0; nt < 8; ++nt) {
#pragma unroll
    for (int kc = 0; kc < 4; ++kc) {
      bf16x8 b = *(const bf16x8*)(Wsw + (size_t)((nt * 4 + kc) * 64 + lane) * 8);
      acc[nt] = __builtin_amdgcn_mfma_f32_16x16x32_bf16(a[kc], b, acc[nt], 0, 0, 0);
    }
  }

  const int rowBase = block_row + wv * 16 + quad * 4;
#pragma unroll
  for (int nt = 0; nt < 8; ++nt) {
    int c = nt * 16 + l15;
    float s = 0.f, q = 0.f;
#pragma unroll
    for (int r = 0; r < 4; ++r) {
      int row = rowBase + r;
      if (row < N) {
        float v = acc[nt][r];
        Y[(size_t)row * D + c] = (bf16_t)v;
        s += v; q += v * v;
      }
    }
    s += __shfl_xor(s, 16); s += __shfl_xor(s, 32);
    q += __shfl_xor(q, 16); q += __shfl_xor(q, 32);
    if (quad == 0) {
      atomicAdd(&sred[c], s);
      atomicAdd(&sred[128 + c], q);
    }
  }
  __syncthreads();
  atomicAdd(&stats[t], sred[t]);
}

// ---------------------------------------------------------------------------
__global__ void bn_finalize(float* __restrict__ stats,
                            const float* __restrict__ gamma,
                            const float* __restrict__ beta,
                            float* __restrict__ ab, float invN) {
  int c = threadIdx.x;
  float mu = stats[c] * invN;
  float var = stats[D + c] * invN - mu * mu;
  var = fmaxf(var, 0.f);
  float inv = rsqrtf(var + BN_EPS);
  float a = gamma[c] * inv;
  ab[c] = a;
  ab[D + c] = beta[c] - mu * a;
  stats[c] = 0.f;
  stats[D + c] = 0.f;
}

// ===========================================================================
// GEMM 2: out = maybe_relu( relu(Y*a + b) @ W + bias )
// Y bf16 in; out bf16 (h') or fp32 (final output)
// ===========================================================================
__global__ __launch_bounds__(256) void gemm2_mfma(
    const bf16_t* __restrict__ Yin, const float* __restrict__ ab,
    const bf16_t* __restrict__ Wsw, const float* __restrict__ bias,
    void* __restrict__ outp, int N, int relu_out, int fp32_out) {
  __shared__ bf16_t As[TR][136];
  const int t = threadIdx.x;
  const int block_row = blockIdx.x * TR;

  for (int i = t; i < TR * 16; i += 256) {
    int r = i >> 4;
    int c = (i & 15) << 3;
    int gr = block_row + r;
    bf16x8 o;
    if (gr < N) {
      bf16x8 p = *(const bf16x8*)(Yin + (size_t)gr * D + c);
#pragma unroll
      for (int j = 0; j < 8; ++j) {
        float v = fmaxf(fmaf((float)p[j], ab[c + j], ab[D + c + j]), 0.f);
        o[j] = (bf16_t)v;
      }
    } else {
#pragma unroll
      for (int j = 0; j < 8; ++j) o[j] = (bf16_t)0.f;
    }
    *(bf16x8*)&As[r][c] = o;
  }
  __syncthreads();

  const int wv = t >> 6;
  const int lane = t & 63;
  const int l15 = lane & 15;
  const int quad = lane >> 4;

  bf16x8 a[4];
#pragma unroll
  for (int kc = 0; kc < 4; ++kc)
    a[kc] = *(const bf16x8*)&As[wv * 16 + l15][kc * 32 + quad * 8];

  floatx4 acc[8];
#pragma unroll
  for (int nt = 0; nt < 8; ++nt) {
    float bv = bias[nt * 16 + l15];
    acc[nt] = (floatx4){bv, bv, bv, bv};
  }

#pragma unroll
  for (int nt = 0; nt < 8; ++nt) {
#pragma unroll
    for (int kc = 0; kc < 4; ++kc) {
      bf16x8 b = *(const bf16x8*)(Wsw + (size_t)((nt * 4 + kc) * 64 + lane) * 8);
      acc[nt] = __builtin_amdgcn_mfma_f32_16x16x32_bf16(a[kc], b, acc[nt], 0, 0, 0);
    }
  }

  const int rowBase = block_row + wv * 16 + quad * 4;
  if (fp32_out) {
    float* out = (float*)outp;
#pragma unroll
    for (int nt = 0; nt < 8; ++nt) {
      int c = nt * 16 + l15;
#pragma unroll
      for (int r = 0; r < 4; ++r) {
        int row = rowBase + r;
        if (row < N) {
          float v = acc[nt][r];
          if (relu_out) v = fmaxf(v, 0.f);
          out[(size_t)row * D + c] = v;
        }
      }
    }
  } else {
    bf16_t* out = (bf16_t*)outp;
#pragma unroll
    for (int nt = 0; nt < 8; ++nt) {
      int c = nt * 16 + l15;
#pragma unroll
      for (int r = 0; r < 4; ++r) {
        int row = rowBase + r;
        if (row < N) {
          float v = acc[nt][r];
          if (relu_out) v = fmaxf(v, 0.f);
          out[(size_t)row * D + c] = (bf16_t)v;
        }
      }
    }
  }
}

// ===========================================================================
extern "C" void kernel_launch(void* const* d_in, const int* in_sizes, int n_in,
                              void* d_out, int out_size, void* d_ws, size_t ws_size,
                              hipStream_t stream) {
  const float* x     = (const float*)d_in[0];
  const float* W1    = (const float*)d_in[1];
  const float* b1    = (const float*)d_in[2];
  const float* gamma = (const float*)d_in[3];
  const float* beta  = (const float*)d_in[4];
  const float* W2    = (const float*)d_in[5];
  const float* b2    = (const float*)d_in[6];
  const int*   ei    = (const int*)d_in[7];

  const int N = in_sizes[0] / D;
  const int E = in_sizes[7] / 2;
  const int* src = ei;
  const int* dst = ei + E;

  char* ws = (char*)d_ws;
  size_t bufBytes = (size_t)N * D * sizeof(bf16_t);   // 12.8 MB
  bf16_t* hb   = (bf16_t*)ws;                          // persistent h (bf16)
  bf16_t* zb   = (bf16_t*)(ws + bufBytes);             // agg output
  bf16_t* Yb   = (bf16_t*)(ws + 2 * bufBytes);         // gemm1 output
  float* stats = (float*)(ws + 3 * bufBytes);          // 256 floats
  float* ab    = stats + 256;                          // 256 floats
  bf16_t* Wsw  = (bf16_t*)(ws + 3 * bufBytes + 2048);  // 6*16384 bf16
  int* row_ptr = (int*)(ws + 3 * bufBytes + 2048 + 6 * 16384 * sizeof(bf16_t));
  int* col     = row_ptr + (N + 1);
  // build-phase scratch aliases zb (first written by layer-0 aggregate, after build)
  int* counts    = (int*)zb;
  int* excl      = counts + N;
  int* cursor    = excl + N;
  int* blockSums = cursor + N;

  const int nb = (N + SCAN_B - 1) / SCAN_B;
  const int eb = (E + 255) / 256;
  const int aggBlocks = (N + 3) / 4;
  const int gemmBlocks = (N + TR - 1) / TR;
  const int n4 = N * D / 4;
  const float invN = 1.f / (float)N;

  // ---- CSR build + conversions ----
  zero_counts<<<(N + 255) / 256, 256, 0, stream>>>(counts, stats, N);
  count_edges<<<eb, 256, 0, stream>>>(dst, counts, E);
  x2b<<<(n4 + 255) / 256, 256, 0, stream>>>(x, hb, n4);
  swizzle_weights<<<(6 * 16384 + 255) / 256, 256, 0, stream>>>(W1, W2, Wsw);
  scan_blocks<<<nb, SCAN_B, 0, stream>>>(counts, excl, blockSums, N);
  scan_tops<<<1, SCAN_B, 0, stream>>>(blockSums, nb);
  add_offsets<<<(N + 255) / 256, 256, 0, stream>>>(excl, blockSums, row_ptr, cursor, N, E);
  fill_edges<<<eb, 256, 0, stream>>>(src, dst, cursor, col, E);

  // ---- layers: agg(hb->zb), gemm1(zb->Yb), bn, gemm2(Yb->hb | out) ----
  for (int i = 0; i < 3; ++i) {
    aggregate<<<aggBlocks, 256, 0, stream>>>(hb, zb, row_ptr, col, N);
    gemm1_mfma<<<gemmBlocks, 256, 0, stream>>>(
        zb, Wsw + (size_t)i * 16384, b1 + (size_t)i * D, Yb, stats, N);
    bn_finalize<<<1, D, 0, stream>>>(stats, gamma + (size_t)i * D,
                                     beta + (size_t)i * D, ab, invN);
    void* Ob = (i == 2) ? d_out : (void*)hb;
    gemm2_mfma<<<gemmBlocks, 256, 0, stream>>>(
        Yb, ab, Wsw + (size_t)(i + 3) * 16384, b2 + (size_t)i * D, Ob, N,
        (i < 2) ? 1 : 0, (i == 2) ? 1 : 0);
  }
}